// Round 4
// baseline (58458.850 us; speedup 1.0000x reference)
//
#include <hip/hip_runtime.h>

#define TSTEPS 512
#define BSZ 256
#define HCH 256

typedef _Float16 f16x8 __attribute__((ext_vector_type(8)));
typedef float    f32x4 __attribute__((ext_vector_type(4)));

// ---------------------------------------------------------------------------
// Design: grid = 16 blocks, each owns 16 batch rows and the ENTIRE gate GEMM
// (16 x 1024, K = IC+256) for those rows -> h, du-dot, skip state, and the
// layer-1 in-place seq overwrite are all block-local. No inter-block sync.
//
// Per step:  A-asm (x frags from regs/global, h frags from H-LDS; fp16 hi/lo)
//         -> MFMA phase (wave g = gate g; 16 col-tiles; 3 split-products per
//            k-tile into one fp32 acc; W hi/lo streamed from L2) -> G-LDS
//         -> sync -> cell phase (gates->c,h; du fp64 dot + shfl tree; u/skip
//            update; nh -> H-LDS hi/lo + seq nt-store) -> sync.
//
// Precision: a*w ~= ah*wh + al*wh + ah*wl (fp16 hi/lo, fp32 MFMA accum):
// dropped al*wl <= 2^-22|aw| -> gate error ~2e-7, fp32-class, so skip
// decisions (nu<0.5) keep reference behavior. du-dot stays fp64.
// ---------------------------------------------------------------------------

// W preprocessing: fp32 -> fp16 hi/lo planes. WW halfs: [grow 1024][plane 2][K]
template<int IC>
__global__ __launch_bounds__(256)
void prep_w(const float* __restrict__ Wih, const float* __restrict__ Whh,
            _Float16* __restrict__ WW)
{
    constexpr int K = IC + HCH;
    const int idx = blockIdx.x * 256 + threadIdx.x;
    if (idx >= 1024 * K) return;
    const int grow = idx / K;
    const int k    = idx - grow * K;
    const float v = (k < IC) ? Wih[(size_t)grow * IC + k]
                             : Whh[(size_t)grow * HCH + (k - IC)];
    const _Float16 hi = (_Float16)v;
    const _Float16 lo = (_Float16)(v - (float)hi);
    WW[((size_t)grow * 2 + 0) * K + k] = hi;
    WW[((size_t)grow * 2 + 1) * K + k] = lo;
}

template<int IC>
__global__ __launch_bounds__(256, 1)
void skiplstm_mfma(const float* __restrict__ x,      // (T, BS, IC)
                   const float* __restrict__ bih, const float* __restrict__ bhh,
                   const float* __restrict__ lw,  const float* __restrict__ lb,
                   const _Float16* __restrict__ WW, // [1024][2][K] halfs
                   float* __restrict__ seq_out,     // (T, BS, H)
                   float* __restrict__ hs_out, float* __restrict__ cs_out,
                   float* __restrict__ skipdu,      // [2][256]
                   int first_layer)
{
    constexpr int K   = IC + HCH;
    constexpr int KT  = K / 32;      // k-tiles
    constexpr int KTX = IC / 32;     // x-region k-tiles
    constexpr int KTH = HCH / 32;    // 8 h-region k-tiles
    constexpr int GP  = 28;          // G row pad: 16B-aligned float4 + 2-way banks
    constexpr int HP  = 264;         // H row pad (halfs)

    __shared__ float    G[4 * 256 * GP];   // gates: [g][hc][row(16) pad 28] f32
    __shared__ _Float16 H[16 * 2 * HP];    // h:     [row][plane][hc pad]   f16
    __shared__ float    BV[1024];          // bih+bhh per gate-col

    const int tid   = threadIdx.x;
    const int g     = tid >> 6;          // wave id = gate index
    const int lane  = tid & 63;
    const int col16 = lane & 15;         // MFMA m/n lane index
    const int lg    = lane >> 4;         // MFMA k-group
    const int row_c = tid >> 4;          // cell-phase row (0..15)
    const int q     = tid & 15;          // cell-phase hc lane
    const int r0    = blockIdx.x * 16;
    const int brow  = r0 + row_c;

    for (int i = tid; i < 1024; i += 256) BV[i] = bih[i] + bhh[i];
    for (int i = tid; i < 16 * 2 * HP; i += 256) H[i] = (_Float16)0.f;

    float c_r[16], h_r[16], lwv[16];
    #pragma unroll
    for (int i = 0; i < 16; ++i) {
        c_r[i] = 0.f; h_r[i] = 0.f;
        lwv[i] = lw[q + 16 * i];
    }
    const float lbv = lb[0];
    float u_r = 1.f, du_r;
    int skip_r;
    if (first_layer) { du_r = 0.f; skip_r = 0; }
    else { du_r = skipdu[brow]; skip_r = (skipdu[BSZ + brow] > 0.5f) ? 1 : 0; }

    // x[0] prefetch into regs (frag layout: row=lane&15, k = kt*32 + lg*8 + e)
    float xv[KTX][8];
    {
        const float* xp = x + ((size_t)0 * BSZ + r0 + col16) * IC + lg * 8;
        #pragma unroll
        for (int kt = 0; kt < KTX; ++kt) {
            const float4 a = *(const float4*)(xp + kt * 32);
            const float4 b = *(const float4*)(xp + kt * 32 + 4);
            xv[kt][0]=a.x; xv[kt][1]=a.y; xv[kt][2]=a.z; xv[kt][3]=a.w;
            xv[kt][4]=b.x; xv[kt][5]=b.y; xv[kt][6]=b.z; xv[kt][7]=b.w;
        }
    }

    f16x8 ah[KT], al[KT];   // persistent A fragments (registers)

    __syncthreads();

    for (int t = 0; t < TSTEPS; ++t) {
        // ---------------- A assembly ----------------
        #pragma unroll
        for (int kt = 0; kt < KTX; ++kt) {       // x-part: split fp32 -> hi/lo
            f16x8 hv, lv;
            #pragma unroll
            for (int e = 0; e < 8; ++e) {
                const float v = xv[kt][e];
                const _Float16 hi = (_Float16)v;
                hv[e] = hi;
                lv[e] = (_Float16)(v - (float)hi);
            }
            ah[kt] = hv; al[kt] = lv;
        }
        #pragma unroll
        for (int kt = 0; kt < KTH; ++kt) {       // h-part: direct f16 frags
            const int off = kt * 32 + lg * 8;
            ah[KTX + kt] = *(const f16x8*)&H[(col16 * 2 + 0) * HP + off];
            al[KTX + kt] = *(const f16x8*)&H[(col16 * 2 + 1) * HP + off];
        }
        // issue x[t+1] loads (complete during MFMA phase)
        if (t + 1 < TSTEPS) {
            const float* xp = x + ((size_t)(t + 1) * BSZ + r0 + col16) * IC + lg * 8;
            #pragma unroll
            for (int kt = 0; kt < KTX; ++kt) {
                const float4 a = *(const float4*)(xp + kt * 32);
                const float4 b = *(const float4*)(xp + kt * 32 + 4);
                xv[kt][0]=a.x; xv[kt][1]=a.y; xv[kt][2]=a.z; xv[kt][3]=a.w;
                xv[kt][4]=b.x; xv[kt][5]=b.y; xv[kt][6]=b.z; xv[kt][7]=b.w;
            }
        }

        // ---------------- MFMA phase: 16 col-tiles in quads ----------------
        for (int cq = 0; cq < 4; ++cq) {
            f32x4 acc[4];
            const _Float16* wb[4];
            #pragma unroll
            for (int cc = 0; cc < 4; ++cc) {
                const int ct   = cq * 4 + cc;
                const int grow = g * 256 + ct * 16 + col16;
                const float bv = BV[grow];
                acc[cc][0] = bv; acc[cc][1] = bv; acc[cc][2] = bv; acc[cc][3] = bv;
                wb[cc] = WW + ((size_t)grow * 2) * K + lg * 8;
            }
            #pragma unroll
            for (int kt = 0; kt < KT; ++kt) {
                f16x8 bh[4], bl[4];
                #pragma unroll
                for (int cc = 0; cc < 4; ++cc) {
                    bh[cc] = *(const f16x8*)(wb[cc] + kt * 32);
                    bl[cc] = *(const f16x8*)(wb[cc] + K + kt * 32);
                }
                #pragma unroll
                for (int cc = 0; cc < 4; ++cc)
                    acc[cc] = __builtin_amdgcn_mfma_f32_16x16x32_f16(ah[kt], bh[cc], acc[cc], 0, 0, 0);
                #pragma unroll
                for (int cc = 0; cc < 4; ++cc)
                    acc[cc] = __builtin_amdgcn_mfma_f32_16x16x32_f16(al[kt], bh[cc], acc[cc], 0, 0, 0);
                #pragma unroll
                for (int cc = 0; cc < 4; ++cc)
                    acc[cc] = __builtin_amdgcn_mfma_f32_16x16x32_f16(ah[kt], bl[cc], acc[cc], 0, 0, 0);
            }
            // C/D: col = lane&15, row = lg*4 + reg  ->  G[g][hc][row0..row0+3]
            #pragma unroll
            for (int cc = 0; cc < 4; ++cc) {
                const int hc = (cq * 4 + cc) * 16 + col16;
                *(f32x4*)&G[(g * 256 + hc) * GP + lg * 4] = acc[cc];
            }
        }
        __syncthreads();

        // ---------------- cell phase ----------------
        const float bu  = rintf(u_r);        // jnp.round == rint
        const float omb = 1.f - bu;
        double s = 0.0;
        #pragma unroll
        for (int i = 0; i < 16; ++i) {
            const int hc = q + 16 * i;
            const float g0 = G[(0 * 256 + hc) * GP + row_c];
            const float g1 = G[(1 * 256 + hc) * GP + row_c];
            const float g2 = G[(2 * 256 + hc) * GP + row_c];
            const float g3 = G[(3 * 256 + hc) * GP + row_c];
            const float si = 1.f / (1.f + expf(-g0));
            const float sf = 1.f / (1.f + expf(-g1));
            const float tg = tanhf(g2);
            const float so = 1.f / (1.f + expf(-g3));
            const float cc_  = sf * c_r[i] + si * tg;
            const float ch_  = so * tanhf(cc_);
            const float nc_n = cc_ * bu;
            const float nh_n = ch_ * bu;
            s += (double)nc_n * (double)lwv[i];   // du dot uses CANDIDATE nc_n
            const float nh = skip_r ? h_r[i] * omb : nh_n;
            const float nc = skip_r ? c_r[i] * omb : nc_n;
            c_r[i] = nc; h_r[i] = nh;
            const _Float16 hh = (_Float16)nh;
            H[(row_c * 2 + 0) * HP + hc] = hh;
            H[(row_c * 2 + 1) * HP + hc] = (_Float16)(nh - (float)hh);
            __builtin_nontemporal_store(nh, seq_out + ((size_t)t * BSZ + brow) * HCH + hc);
        }
        s += __shfl_xor(s, 1);
        s += __shfl_xor(s, 2);
        s += __shfl_xor(s, 4);
        s += __shfl_xor(s, 8);               // all 16 q-lanes: full-HC row sum
        const float du_n = 1.f / (1.f + expf(-(float)(s + (double)lbv)));
        float nu, ndu;
        if (skip_r) { nu = fminf(fmaxf(u_r + du_r, 0.f), 1.f) * omb; ndu = du_r; }
        else        { nu = du_n * bu;  ndu = du_n; }
        u_r = nu; du_r = ndu;
        skip_r = (nu < 0.5f) ? 1 : 0;        // == (ceil(0.5/nu)-1 > 0)
        __syncthreads();                      // H ready, G reusable
    }

    #pragma unroll
    for (int i = 0; i < 16; ++i) {
        hs_out[(size_t)brow * HCH + q + 16 * i] = h_r[i];
        cs_out[(size_t)brow * HCH + q + 16 * i] = c_r[i];
    }
    if (first_layer && q == 0) {
        skipdu[brow]       = du_r;
        skipdu[BSZ + brow] = skip_r ? 1.f : 0.f;
    }
}

extern "C" void kernel_launch(void* const* d_in, const int* in_sizes, int n_in,
                              void* d_out, int out_size, void* d_ws, size_t ws_size,
                              hipStream_t stream)
{
    (void)in_sizes; (void)n_in; (void)out_size; (void)ws_size;

    const float* x    = (const float*)d_in[0];
    const float* Wih0 = (const float*)d_in[1];
    const float* Whh0 = (const float*)d_in[2];
    const float* bih0 = (const float*)d_in[3];
    const float* bhh0 = (const float*)d_in[4];
    const float* lw0  = (const float*)d_in[5];
    const float* lb0  = (const float*)d_in[6];
    const float* Wih1 = (const float*)d_in[7];
    const float* Whh1 = (const float*)d_in[8];
    const float* bih1 = (const float*)d_in[9];
    const float* bhh1 = (const float*)d_in[10];
    const float* lw1  = (const float*)d_in[11];
    const float* lb1  = (const float*)d_in[12];

    float* out = (float*)d_out;
    float* seq = out;                                   // (512,256,256)
    float* hs0 = out + (size_t)512 * 256 * 256;
    float* hs1 = hs0 + 256 * 256;
    float* cs0 = hs1 + 256 * 256;
    float* cs1 = cs0 + 256 * 256;

    _Float16* WW     = (_Float16*)d_ws;                        // 2 MiB (reused)
    float*    skipdu = (float*)((char*)d_ws + 2u * 1024 * 1024); // 2 KiB

    // layer 0 (IC=128, K=384)
    prep_w<128><<<dim3(1024 * 384 / 256), dim3(256), 0, stream>>>(Wih0, Whh0, WW);
    skiplstm_mfma<128><<<dim3(16), dim3(256), 0, stream>>>(
        x, bih0, bhh0, lw0, lb0, WW, seq, hs0, cs0, skipdu, 1);

    // layer 1 (IC=256, K=512) — input = layer-0 output, in place
    prep_w<256><<<dim3(1024 * 512 / 256), dim3(256), 0, stream>>>(Wih1, Whh1, WW);
    skiplstm_mfma<256><<<dim3(16), dim3(256), 0, stream>>>(
        seq, bih1, bhh1, lw1, lb1, WW, seq, hs1, cs1, skipdu, 0);
}

// Round 5
// 13553.999 us; speedup vs baseline: 4.3130x; 4.3130x over previous
//
#include <hip/hip_runtime.h>

#define TSTEPS 512
#define BSZ 256
#define HCH 256

typedef _Float16 f16x8 __attribute__((ext_vector_type(8)));
typedef _Float16 f16x4 __attribute__((ext_vector_type(4)));
typedef float    f32x4 __attribute__((ext_vector_type(4)));

__device__ __forceinline__ float sigmoidf_(float v) { return 1.f / (1.f + expf(-v)); }

// 256 blocks = 16 groups (btile = bid&15; all 16 blocks of a group share
// bid%8 -> same XCD under round-robin) x 16 jtiles. Block owns 64 gate-cols
// (4 gates x 16 hc) for its group's 16 batch rows. W slice fp16 hi/lo in LDS
// (staged once). Gates via mfma_f32_16x16x32_f16, 3-product hi/lo split
// (~22-bit mantissa, validated in round 4). h exchanged as packed f16 hi/lo
// planes (readable directly as A-fragments). du-dot via fp64 partials;
// u/du/skip update deferred one step (after partials cross the barrier) --
// algebraically identical to the reference scan. One flag barrier per step;
// x-part MFMAs overlap the barrier wait.
template<int IC>
__global__ __launch_bounds__(256, 1)
void skiplstm(const float* __restrict__ x,
              const float* __restrict__ Wih, const float* __restrict__ Whh,
              const float* __restrict__ bih, const float* __restrict__ bhh,
              const float* __restrict__ lw,  const float* __restrict__ lb,
              float* __restrict__ seq_out,
              float* __restrict__ hs_out, float* __restrict__ cs_out,
              _Float16* __restrict__ hpl,    // [2][16][2][16][256] halfs
              double* __restrict__ part,     // [2][16][16][16] doubles
              float* __restrict__ skipdu,    // [2][256]
              unsigned* __restrict__ flags,  // [2][16][16]
              int first_layer)
{
    constexpr int K   = IC + HCH;
    constexpr int KP  = K + 8;           // +8 halfs: 2-way-max LDS banks
    constexpr int ICP = IC + 8;
    constexpr int KTX = IC / 32;
    constexpr int KTH = HCH / 32;

    __shared__ _Float16 Wh [64][KP];     // W hi plane
    __shared__ _Float16 Wl_[64][KP];     // W lo plane
    __shared__ _Float16 XSh[16][ICP];    // x-slab hi
    __shared__ _Float16 XSl[16][ICP];    // x-slab lo
    __shared__ float    G[64][20];       // gates [col][row pad20]
    __shared__ float    BV[64];

    const int tid   = threadIdx.x;
    const int bid   = blockIdx.x;
    const int btile = bid & 15;          // group id
    const int jtile = bid >> 4;
    // MFMA-role indices
    const int g    = tid >> 6;           // wave = gate
    const int lane = tid & 63;
    const int n16  = lane & 15;          // A-row / B-col lane index
    const int lg   = lane >> 4;          // k-group
    const int c_   = g * 16 + n16;       // block-local gate-col
    // cell-role indices
    const int row_c = tid >> 4;
    const int q     = tid & 15;
    const int J     = jtile * 16 + q;
    const int brow  = btile * 16 + row_c;
    const int r0    = btile * 16;

    unsigned* gfl    = flags + (first_layer ? 0 : 256) + btile * 16;
    unsigned* myflag = gfl + jtile;

    // ---- one-time: stage W slice fp32 -> fp16 hi/lo planes ----
    for (int i4 = tid; i4 < 64 * (K / 4); i4 += 256) {
        const int c = i4 / (K / 4);
        const int k = (i4 - c * (K / 4)) * 4;
        const int grow = (c >> 4) * HCH + jtile * 16 + (c & 15);
        const float4 v = (k < IC)
            ? *(const float4*)(Wih + (size_t)grow * IC  + k)
            : *(const float4*)(Whh + (size_t)grow * HCH + (k - IC));
        f16x4 hi, lo;
        hi[0] = (_Float16)v.x; lo[0] = (_Float16)(v.x - (float)hi[0]);
        hi[1] = (_Float16)v.y; lo[1] = (_Float16)(v.y - (float)hi[1]);
        hi[2] = (_Float16)v.z; lo[2] = (_Float16)(v.z - (float)hi[2]);
        hi[3] = (_Float16)v.w; lo[3] = (_Float16)(v.w - (float)hi[3]);
        *(f16x4*)&Wh [c][k] = hi;
        *(f16x4*)&Wl_[c][k] = lo;
    }
    if (tid < 64) {
        const int grow = (tid >> 4) * HCH + jtile * 16 + (tid & 15);
        BV[tid] = bih[grow] + bhh[grow];
    }

    const float lwv = lw[J];
    const float lbv = lb[0];
    float h_r = 0.f, c_r = 0.f, u_r = 1.f, du_r;
    int skip_r;
    if (first_layer) { du_r = 0.f; skip_r = 0; }
    else { du_r = skipdu[brow]; skip_r = (skipdu[BSZ + brow] > 0.5f) ? 1 : 0; }

    // h(-1) = 0 planes at parity 1
    hpl[((((size_t)1 * 16 + btile) * 2 + 0) * 16 + row_c) * 256 + J] = (_Float16)0.f;
    hpl[((((size_t)1 * 16 + btile) * 2 + 1) * 16 + row_c) * 256 + J] = (_Float16)0.f;

    auto stage_x = [&](int t) {
        for (int i4 = tid; i4 < 16 * (IC / 4); i4 += 256) {
            const int row = i4 / (IC / 4);
            const int k   = (i4 - row * (IC / 4)) * 4;
            const float4 v = *(const float4*)(x + ((size_t)t * BSZ + r0 + row) * IC + k);
            f16x4 hi, lo;
            hi[0] = (_Float16)v.x; lo[0] = (_Float16)(v.x - (float)hi[0]);
            hi[1] = (_Float16)v.y; lo[1] = (_Float16)(v.y - (float)hi[1]);
            hi[2] = (_Float16)v.z; lo[2] = (_Float16)(v.z - (float)hi[2]);
            hi[3] = (_Float16)v.w; lo[3] = (_Float16)(v.w - (float)hi[3]);
            *(f16x4*)&XSh[row][k] = hi;
            *(f16x4*)&XSl[row][k] = lo;
        }
    };

    auto arrive = [&](unsigned val) {
        asm volatile("s_waitcnt vmcnt(0) lgkmcnt(0)" ::: "memory");
        __syncthreads();
        if (tid == 0) {
            __builtin_amdgcn_fence(__ATOMIC_RELEASE, "agent");
            __hip_atomic_store(myflag, val, __ATOMIC_RELAXED, __HIP_MEMORY_SCOPE_AGENT);
        }
    };
    auto wait_ = [&](unsigned val) {
        if (tid < 16)
            while (__hip_atomic_load(gfl + tid, __ATOMIC_RELAXED,
                                     __HIP_MEMORY_SCOPE_AGENT) < val)
                __builtin_amdgcn_s_sleep(1);
        __syncthreads();
        __builtin_amdgcn_fence(__ATOMIC_ACQUIRE, "agent");
    };

    f32x4 accA, accB;
    auto xmfma = [&]() {   // gates x-part: bias + x @ Wih^T  (h-independent)
        const float bv = BV[c_];
        accA = f32x4{bv, bv, bv, bv};
        accB = f32x4{0.f, 0.f, 0.f, 0.f};
        #pragma unroll
        for (int kt = 0; kt < KTX; ++kt) {
            const int ko = kt * 32 + lg * 8;
            const f16x8 ah = *(const f16x8*)&XSh[n16][ko];
            const f16x8 al = *(const f16x8*)&XSl[n16][ko];
            const f16x8 bh = *(const f16x8*)&Wh [c_][ko];
            const f16x8 bl = *(const f16x8*)&Wl_[c_][ko];
            accA = __builtin_amdgcn_mfma_f32_16x16x32_f16(ah, bh, accA, 0, 0, 0);
            accB = __builtin_amdgcn_mfma_f32_16x16x32_f16(al, bh, accB, 0, 0, 0);
            accB = __builtin_amdgcn_mfma_f32_16x16x32_f16(ah, bl, accB, 0, 0, 0);
        }
    };

    auto u_update = [&](const double* pp) {   // consume part(t-1), advance u/du/skip
        double s = pp[tid];                    // [row_c][q] coalesced
        s += __shfl_xor(s, 1); s += __shfl_xor(s, 2);
        s += __shfl_xor(s, 4); s += __shfl_xor(s, 8);
        const float du_n = sigmoidf_((float)(s + (double)lbv));
        const float bu_p = rintf(u_r);
        float nu, ndu;
        if (skip_r) { nu = fminf(fmaxf(u_r + du_r, 0.f), 1.f) * (1.f - bu_p); ndu = du_r; }
        else        { nu = du_n * bu_p; ndu = du_n; }
        u_r = nu; du_r = ndu;
        skip_r = (nu < 0.5f) ? 1 : 0;          // == (ceil(0.5/nu)-1 > 0)
    };

    // ---- prologue: layer1 stages x(0) pre-arrive (in-place safety) ----
    if (IC != 128) stage_x(0);
    arrive(1);
    if (IC == 128) { stage_x(0); __syncthreads(); }
    xmfma();
    wait_(1);

    for (int t = 0; t < TSTEPS; ++t) {
        const int par  = t & 1;
        const int rpar = 1 - par;

        // issue h(t-1) fragment loads first (L2, hide under u-update)
        f16x8 hfh[KTH], hfl[KTH];
        {
            const _Float16* ph = hpl + ((((size_t)rpar * 16 + btile) * 2 + 0) * 16 + n16) * 256 + lg * 8;
            const _Float16* pl = hpl + ((((size_t)rpar * 16 + btile) * 2 + 1) * 16 + n16) * 256 + lg * 8;
            #pragma unroll
            for (int ht = 0; ht < KTH; ++ht) {
                hfh[ht] = *(const f16x8*)(ph + ht * 32);
                hfl[ht] = *(const f16x8*)(pl + ht * 32);
            }
        }
        if (t > 0) u_update(part + ((size_t)rpar * 16 + btile) * 256);

        // gates h-part MFMAs (W from LDS)
        #pragma unroll
        for (int ht = 0; ht < KTH; ++ht) {
            const int ko = IC + ht * 32 + lg * 8;
            const f16x8 bh = *(const f16x8*)&Wh [c_][ko];
            const f16x8 bl = *(const f16x8*)&Wl_[c_][ko];
            accA = __builtin_amdgcn_mfma_f32_16x16x32_f16(hfh[ht], bh, accA, 0, 0, 0);
            accB = __builtin_amdgcn_mfma_f32_16x16x32_f16(hfl[ht], bh, accB, 0, 0, 0);
            accB = __builtin_amdgcn_mfma_f32_16x16x32_f16(hfh[ht], bl, accB, 0, 0, 0);
        }
        {
            const f32x4 acc = accA + accB;
            *(f32x4*)&G[c_][lg * 4] = acc;    // C/D: col=lane&15, row=lg*4+reg
        }
        __syncthreads();

        // ---- cell (1 thread = 1 (row,hc) cell) ----
        const float bu  = rintf(u_r);          // jnp.round == rint (half-even)
        const float omb = 1.f - bu;
        const float g0 = G[ 0 + q][row_c];
        const float g1 = G[16 + q][row_c];
        const float g2 = G[32 + q][row_c];
        const float g3 = G[48 + q][row_c];
        const float si = sigmoidf_(g0);
        const float sf = sigmoidf_(g1);
        const float tg = tanhf(g2);
        const float so = sigmoidf_(g3);
        const float cc_ = sf * c_r + si * tg;
        const float ch_ = so * tanhf(cc_);
        const float nc_n = cc_ * bu;
        const float nh_n = ch_ * bu;
        const float nh = skip_r ? h_r * omb : nh_n;
        const float nc = skip_r ? c_r * omb : nc_n;
        h_r = nh; c_r = nc;
        __builtin_nontemporal_store(nh, seq_out + ((size_t)t * BSZ + brow) * HCH + J);
        {
            const _Float16 hh = (_Float16)nh;
            const _Float16 hl = (_Float16)(nh - (float)hh);
            hpl[((((size_t)par * 16 + btile) * 2 + 0) * 16 + row_c) * 256 + J] = hh;
            hpl[((((size_t)par * 16 + btile) * 2 + 1) * 16 + row_c) * 256 + J] = hl;
        }
        double dd = (double)nc_n * (double)lwv;  // du-dot uses CANDIDATE nc_n
        dd += __shfl_xor(dd, 1); dd += __shfl_xor(dd, 2);
        dd += __shfl_xor(dd, 4); dd += __shfl_xor(dd, 8);
        if (q == 0)
            part[((size_t)par * 16 + btile) * 256 + row_c * 16 + jtile] = dd;

        // layer1: stage x(t+1)=seq(t+1) PRE-arrive -> reads drained by the
        // arrive vmcnt(0), so cross-block seq[t+1] writes (cell t+1, post-
        // barrier) cannot race them. layer0: x immutable, stage in overlap.
        const bool more = (t + 1 < TSTEPS);
        if (IC != 128 && more) stage_x(t + 1);
        arrive((unsigned)(t + 2));
        if (more) {
            if (IC == 128) { stage_x(t + 1); __syncthreads(); }
            xmfma();                          // overlaps other blocks' arrival
        }
        wait_((unsigned)(t + 2));
    }

    // final u/du/skip update (partials of t=511 crossed the last barrier)
    u_update(part + ((size_t)((TSTEPS - 1) & 1) * 16 + btile) * 256);

    hs_out[(size_t)brow * HCH + J] = h_r;
    cs_out[(size_t)brow * HCH + J] = c_r;
    if (first_layer && jtile == 0 && q == 0) {
        skipdu[brow]       = du_r;
        skipdu[BSZ + brow] = skip_r ? 1.f : 0.f;
    }
}

extern "C" void kernel_launch(void* const* d_in, const int* in_sizes, int n_in,
                              void* d_out, int out_size, void* d_ws, size_t ws_size,
                              hipStream_t stream)
{
    (void)in_sizes; (void)n_in; (void)out_size; (void)ws_size;

    const float* x    = (const float*)d_in[0];
    const float* Wih0 = (const float*)d_in[1];
    const float* Whh0 = (const float*)d_in[2];
    const float* bih0 = (const float*)d_in[3];
    const float* bhh0 = (const float*)d_in[4];
    const float* lw0  = (const float*)d_in[5];
    const float* lb0  = (const float*)d_in[6];
    const float* Wih1 = (const float*)d_in[7];
    const float* Whh1 = (const float*)d_in[8];
    const float* bih1 = (const float*)d_in[9];
    const float* bhh1 = (const float*)d_in[10];
    const float* lw1  = (const float*)d_in[11];
    const float* lb1  = (const float*)d_in[12];

    float* out = (float*)d_out;
    float* seq = out;                                   // (512,256,256)
    float* hs0 = out + (size_t)512 * 256 * 256;
    float* hs1 = hs0 + 256 * 256;
    float* cs0 = hs1 + 256 * 256;
    float* cs1 = cs0 + 256 * 256;

    char* ws = (char*)d_ws;
    _Float16* hpl    = (_Float16*)ws;                           // 524288 B
    double*   part   = (double*)  (ws + 524288);                //  65536 B
    float*    skipdu = (float*)   (ws + 524288 + 65536);        //   2048 B
    unsigned* flags  = (unsigned*)(ws + 524288 + 65536 + 2048); //   2048 B

    hipMemsetAsync(flags, 0, 2 * 256 * sizeof(unsigned), stream);

    int one = 1, zero = 0;
    {
        void* args[] = { (void*)&x,   (void*)&Wih0, (void*)&Whh0, (void*)&bih0,
                         (void*)&bhh0,(void*)&lw0,  (void*)&lb0,  (void*)&seq,
                         (void*)&hs0, (void*)&cs0,  (void*)&hpl,  (void*)&part,
                         (void*)&skipdu, (void*)&flags, (void*)&one };
        hipLaunchCooperativeKernel(reinterpret_cast<void*>(skiplstm<128>),
                                   dim3(256), dim3(256), args, 0, stream);
    }
    {
        const float* x1 = seq;   // layer-1 input = layer-0 output, in place
        void* args[] = { (void*)&x1,  (void*)&Wih1, (void*)&Whh1, (void*)&bih1,
                         (void*)&bhh1,(void*)&lw1,  (void*)&lb1,  (void*)&seq,
                         (void*)&hs1, (void*)&cs1,  (void*)&hpl,  (void*)&part,
                         (void*)&skipdu, (void*)&flags, (void*)&zero };
        hipLaunchCooperativeKernel(reinterpret_cast<void*>(skiplstm<256>),
                                   dim3(256), dim3(256), args, 0, stream);
    }
}

// Round 6
// 4471.341 us; speedup vs baseline: 13.0741x; 3.0313x over previous
//
#include <hip/hip_runtime.h>

#define TSTEPS 512
#define BSZ 256
#define HCH 256

typedef _Float16 f16x8 __attribute__((ext_vector_type(8)));
typedef _Float16 f16x4 __attribute__((ext_vector_type(4)));
typedef float    f32x4 __attribute__((ext_vector_type(4)));

__device__ __forceinline__ float sigmoidf_(float v) { return 1.f / (1.f + expf(-v)); }
__device__ __forceinline__ unsigned pack2h(_Float16 a, _Float16 b) {
    union { _Float16 h[2]; unsigned u; } x; x.h[0] = a; x.h[1] = b; return x.u;
}

// 256 blocks = 16 groups (btile=bid&15) x 16 jtiles. Block owns 64 gate-cols
// for its group's 16 batch rows; W fp16 hi/lo slice LDS-resident. Gates via
// mfma_f32_16x16x32_f16 3-product hi/lo split (validated r4/r5).
// FENCE-FREE group barrier: all cross-block payload (h planes packed u32,
// du partials as doubles) moves via relaxed AGENT-scope atomics (cache-
// bypassing, same mechanism as the proven flags). Release = s_waitcnt
// vmcnt(0) then flag store; acquire = poll then bypassing loads. No
// buffer_wbl2 / buffer_inv per step -> L2 stays warm for x/W/seq.
// LDS pool (16.9 KB) time-shares Hs (h planes) -> G (gates) -> XS (x slab);
// lifetimes disjoint, role switches guarded by __syncthreads.
template<int IC>
__global__ __launch_bounds__(256, 1)
void skiplstm(const float* __restrict__ x,
              const float* __restrict__ Wih, const float* __restrict__ Whh,
              const float* __restrict__ bih, const float* __restrict__ bhh,
              const float* __restrict__ lw,  const float* __restrict__ lb,
              float* __restrict__ seq_out,
              float* __restrict__ hs_out, float* __restrict__ cs_out,
              unsigned* __restrict__ hG,     // [2][16][2 planes][16][128] u32
              double* __restrict__ part,     // [2][16][16][16]
              float* __restrict__ skipdu,    // [2][256]
              unsigned* __restrict__ flags,  // [2][256]
              int first_layer)
{
    constexpr bool FIRST = (IC == 128);
    constexpr int K   = IC + HCH;
    constexpr int KP  = K + 8;
    constexpr int ICP = IC + 8;
    constexpr int KTX = IC / 32;
    constexpr int KTH = HCH / 32;
    constexpr int HS_BYTES = 2 * 16 * 264 * 2;      // two f16 planes [16][264]
    constexpr int XS_BYTES = 2 * 16 * ICP * 2;
    constexpr int POOL = (HS_BYTES > XS_BYTES) ? HS_BYTES : XS_BYTES;

    __shared__ _Float16 Wh [64][KP];
    __shared__ _Float16 Wl_[64][KP];
    __shared__ float    BV[64];
    __shared__ __align__(16) char pool[POOL];

    _Float16 (*Hsh)[264] = (_Float16(*)[264])pool;               // role 1
    _Float16 (*Hsl)[264] = (_Float16(*)[264])(pool + 16*264*2);
    float    (*G)[20]    = (float(*)[20])pool;                   // role 2
    _Float16 (*XSh)[ICP] = (_Float16(*)[ICP])pool;               // role 3
    _Float16 (*XSl)[ICP] = (_Float16(*)[ICP])(pool + 16*ICP*2);

    const int tid   = threadIdx.x;
    const int bid   = blockIdx.x;
    const int btile = bid & 15;
    const int jtile = bid >> 4;
    const int lane  = tid & 63;
    const int g     = tid >> 6;          // wave = gate
    const int n16   = lane & 15;
    const int lg    = lane >> 4;
    const int c_    = g * 16 + n16;      // block-local gate col
    const int row_c = tid >> 4;
    const int q     = tid & 15;
    const int J     = jtile * 16 + q;
    const int brow  = btile * 16 + row_c;
    const int r0    = btile * 16;

    unsigned* gfl    = flags + (FIRST ? 0 : 256) + btile * 16;
    unsigned* myflag = gfl + jtile;

    // ---- one-time: W slice fp32 -> fp16 hi/lo planes in LDS ----
    for (int i4 = tid; i4 < 64 * (K / 4); i4 += 256) {
        const int c = i4 / (K / 4);
        const int k = (i4 - c * (K / 4)) * 4;
        const int grow = (c >> 4) * HCH + jtile * 16 + (c & 15);
        const float4 v = (k < IC)
            ? *(const float4*)(Wih + (size_t)grow * IC  + k)
            : *(const float4*)(Whh + (size_t)grow * HCH + (k - IC));
        f16x4 hi, lo;
        hi[0] = (_Float16)v.x; lo[0] = (_Float16)(v.x - (float)hi[0]);
        hi[1] = (_Float16)v.y; lo[1] = (_Float16)(v.y - (float)hi[1]);
        hi[2] = (_Float16)v.z; lo[2] = (_Float16)(v.z - (float)hi[2]);
        hi[3] = (_Float16)v.w; lo[3] = (_Float16)(v.w - (float)hi[3]);
        *(f16x4*)&Wh [c][k] = hi;
        *(f16x4*)&Wl_[c][k] = lo;
    }
    if (tid < 64) {
        const int grow = (tid >> 4) * HCH + jtile * 16 + (tid & 15);
        BV[tid] = bih[grow] + bhh[grow];
    }

    const float lwv = lw[J];
    const float lbv = lb[0];
    float h_r = 0.f, c_r = 0.f, u_r = 1.f, du_r;
    int skip_r;
    if (FIRST) { du_r = 0.f; skip_r = 0; }
    else { du_r = skipdu[brow]; skip_r = (skipdu[BSZ + brow] > 0.5f) ? 1 : 0; }

    auto stage_x = [&](int t) {
        for (int i4 = tid; i4 < 16 * (IC / 4); i4 += 256) {
            const int row = i4 / (IC / 4);
            const int k   = (i4 - row * (IC / 4)) * 4;
            const float4 v = *(const float4*)(x + ((size_t)t * BSZ + r0 + row) * IC + k);
            f16x4 hi, lo;
            hi[0] = (_Float16)v.x; lo[0] = (_Float16)(v.x - (float)hi[0]);
            hi[1] = (_Float16)v.y; lo[1] = (_Float16)(v.y - (float)hi[1]);
            hi[2] = (_Float16)v.z; lo[2] = (_Float16)(v.z - (float)hi[2]);
            hi[3] = (_Float16)v.w; lo[3] = (_Float16)(v.w - (float)hi[3]);
            *(f16x4*)&XSh[row][k] = hi;
            *(f16x4*)&XSl[row][k] = lo;
        }
    };

    auto arrive = [&](unsigned val) {
        asm volatile("s_waitcnt vmcnt(0) lgkmcnt(0)" ::: "memory");  // payload ack'd
        __syncthreads();
        if (tid == 0)
            __hip_atomic_store(myflag, val, __ATOMIC_RELAXED, __HIP_MEMORY_SCOPE_AGENT);
    };
    auto wait_ = [&](unsigned val) {
        if (tid < 16)
            while (__hip_atomic_load(gfl + tid, __ATOMIC_RELAXED,
                                     __HIP_MEMORY_SCOPE_AGENT) < val)
                __builtin_amdgcn_s_sleep(1);
        __syncthreads();
        asm volatile("" ::: "memory");
    };

    f32x4 accA, accB;
    auto xmfma = [&]() {   // bias + x-part (h-independent), from XS pool role
        const float bv = BV[c_];
        accA = f32x4{bv, bv, bv, bv};
        accB = f32x4{0.f, 0.f, 0.f, 0.f};
        #pragma unroll
        for (int kt = 0; kt < KTX; ++kt) {
            const int ko = kt * 32 + lg * 8;
            const f16x8 ah = *(const f16x8*)&XSh[n16][ko];
            const f16x8 al = *(const f16x8*)&XSl[n16][ko];
            const f16x8 bh = *(const f16x8*)&Wh [c_][ko];
            const f16x8 bl = *(const f16x8*)&Wl_[c_][ko];
            accA = __builtin_amdgcn_mfma_f32_16x16x32_f16(ah, bh, accA, 0, 0, 0);
            accB = __builtin_amdgcn_mfma_f32_16x16x32_f16(al, bh, accB, 0, 0, 0);
            accB = __builtin_amdgcn_mfma_f32_16x16x32_f16(ah, bl, accB, 0, 0, 0);
        }
    };

    auto u_advance = [&](double ps) {      // consume part(t-1): u/du/skip -> step t
        double s = ps;
        s += __shfl_xor(s, 1); s += __shfl_xor(s, 2);
        s += __shfl_xor(s, 4); s += __shfl_xor(s, 8);
        const float du_n = sigmoidf_((float)(s + (double)lbv));
        const float bu_p = rintf(u_r);
        float nu, ndu;
        if (skip_r) { nu = fminf(fmaxf(u_r + du_r, 0.f), 1.f) * (1.f - bu_p); ndu = du_r; }
        else        { nu = du_n * bu_p; ndu = du_n; }
        u_r = nu; du_r = ndu;
        skip_r = (nu < 0.5f) ? 1 : 0;      // == (ceil(0.5/nu)-1 > 0)
    };

    // ---- prologue ----
    if (!FIRST) stage_x(0);                 // layer1: pre-arrive (in-place safety)
    arrive(1);
    if (FIRST) { stage_x(0); __syncthreads(); }
    xmfma();
    wait_(1);

    for (int t = 0; t < TSTEPS; ++t) {
        const int par  = t & 1;
        const int rpar = par ^ 1;

        // ---- pool role 1: Hs = h(t-1) planes ----
        if (t == 0) {
            for (int i = tid; i < HS_BYTES / 4; i += 256) ((unsigned*)pool)[i] = 0u;
            __syncthreads();
        } else {
            const size_t hb = ((size_t)(rpar * 16 + btile)) * 2 * 2048;
            unsigned vh[8], vl[8];
            #pragma unroll
            for (int i = 0; i < 8; ++i) {
                vh[i] = __hip_atomic_load(hG + hb + tid + i * 256,
                                          __ATOMIC_RELAXED, __HIP_MEMORY_SCOPE_AGENT);
                vl[i] = __hip_atomic_load(hG + hb + 2048 + tid + i * 256,
                                          __ATOMIC_RELAXED, __HIP_MEMORY_SCOPE_AGENT);
            }
            const double ps = __hip_atomic_load(
                part + ((size_t)rpar * 16 + btile) * 256 + tid,
                __ATOMIC_RELAXED, __HIP_MEMORY_SCOPE_AGENT);
            #pragma unroll
            for (int i = 0; i < 8; ++i) {
                const int w = tid + i * 256;
                *(unsigned*)&Hsh[w >> 7][(w & 127) * 2] = vh[i];
                *(unsigned*)&Hsl[w >> 7][(w & 127) * 2] = vl[i];
            }
            u_advance(ps);
            __syncthreads();
        }

        // h fragments from LDS planes (f16x8, layout matches MFMA A-frag)
        f16x8 hfh[KTH], hfl[KTH];
        #pragma unroll
        for (int ht = 0; ht < KTH; ++ht) {
            hfh[ht] = *(const f16x8*)&Hsh[n16][ht * 32 + lg * 8];
            hfl[ht] = *(const f16x8*)&Hsl[n16][ht * 32 + lg * 8];
        }
        __syncthreads();                   // Hs dead -> pool becomes G

        // gates h-part MFMAs
        #pragma unroll
        for (int ht = 0; ht < KTH; ++ht) {
            const int ko = IC + ht * 32 + lg * 8;
            const f16x8 bh = *(const f16x8*)&Wh [c_][ko];
            const f16x8 bl = *(const f16x8*)&Wl_[c_][ko];
            accA = __builtin_amdgcn_mfma_f32_16x16x32_f16(hfh[ht], bh, accA, 0, 0, 0);
            accB = __builtin_amdgcn_mfma_f32_16x16x32_f16(hfl[ht], bh, accB, 0, 0, 0);
            accB = __builtin_amdgcn_mfma_f32_16x16x32_f16(hfh[ht], bl, accB, 0, 0, 0);
        }
        {
            const f32x4 acc = accA + accB;
            *(f32x4*)&G[c_][lg * 4] = acc;   // C/D: col=lane&15, row=lg*4+reg
        }
        __syncthreads();

        // ---- cell ----
        const float bu  = rintf(u_r);        // jnp.round == rint (half-even)
        const float omb = 1.f - bu;
        const float g0 = G[ 0 + q][row_c];
        const float g1 = G[16 + q][row_c];
        const float g2 = G[32 + q][row_c];
        const float g3 = G[48 + q][row_c];
        const float si = sigmoidf_(g0);
        const float sf = sigmoidf_(g1);
        const float tg = tanhf(g2);
        const float so = sigmoidf_(g3);
        const float cc_ = sf * c_r + si * tg;
        const float ch_ = so * tanhf(cc_);
        const float nc_n = cc_ * bu;
        const float nh_n = ch_ * bu;
        const float nh = skip_r ? h_r * omb : nh_n;
        const float nc = skip_r ? c_r * omb : nc_n;
        h_r = nh; c_r = nc;

        // packed h hi/lo -> bypassing store (1 u32/thread; lane pairing)
        const _Float16 hh = (_Float16)nh;
        const _Float16 hl = (_Float16)(nh - (float)hh);
        const unsigned hbits = pack2h(hh, hl);
        const unsigned pbits = (unsigned)__shfl_xor((int)hbits, 1);
        const unsigned word  = (q & 1) ? ((pbits >> 16) | (hbits & 0xffff0000u))
                                       : ((hbits & 0xffffu) | (pbits << 16));
        const size_t wb = (((size_t)par * 16 + btile) * 2 + (q & 1)) * 2048
                        + (size_t)row_c * 128 + (J >> 1);
        __hip_atomic_store(hG + wb, word, __ATOMIC_RELAXED, __HIP_MEMORY_SCOPE_AGENT);

        double dd = (double)nc_n * (double)lwv;   // du-dot uses CANDIDATE nc_n
        dd += __shfl_xor(dd, 1); dd += __shfl_xor(dd, 2);
        dd += __shfl_xor(dd, 4); dd += __shfl_xor(dd, 8);
        if (q == 0)
            __hip_atomic_store(part + ((size_t)par * 16 + btile) * 256 + row_c * 16 + jtile,
                               dd, __ATOMIC_RELAXED, __HIP_MEMORY_SCOPE_AGENT);
        __syncthreads();                   // G dead -> pool becomes XS

        // layer1 stages x(t+1)=seq(t+1) PRE-arrive: reads drained by arrive's
        // vmcnt(0) before flag(t+2); writers store seq(t+1) only after their
        // arrive(t+3) > wait(t+2) -> race-free. layer0: x immutable.
        const bool more = (t + 1 < TSTEPS);
        if (!FIRST && more) stage_x(t + 1);
        arrive((unsigned)(t + 2));
        // overlap window: seq store (2 barriers of slack) + x-part MFMAs
        __builtin_nontemporal_store(nh, seq_out + ((size_t)t * BSZ + brow) * HCH + J);
        if (more) {
            if (FIRST) { stage_x(t + 1); __syncthreads(); }
            xmfma();
        }
        wait_((unsigned)(t + 2));
    }

    // final u/du/skip advance (part(511) flagged by the last barrier)
    {
        const double ps = __hip_atomic_load(
            part + ((size_t)((TSTEPS - 1) & 1) * 16 + btile) * 256 + tid,
            __ATOMIC_RELAXED, __HIP_MEMORY_SCOPE_AGENT);
        u_advance(ps);
    }

    hs_out[(size_t)brow * HCH + J] = h_r;
    cs_out[(size_t)brow * HCH + J] = c_r;
    if (FIRST && jtile == 0 && q == 0) {
        skipdu[brow]       = du_r;
        skipdu[BSZ + brow] = skip_r ? 1.f : 0.f;
    }
}

extern "C" void kernel_launch(void* const* d_in, const int* in_sizes, int n_in,
                              void* d_out, int out_size, void* d_ws, size_t ws_size,
                              hipStream_t stream)
{
    (void)in_sizes; (void)n_in; (void)out_size; (void)ws_size;

    const float* x    = (const float*)d_in[0];
    const float* Wih0 = (const float*)d_in[1];
    const float* Whh0 = (const float*)d_in[2];
    const float* bih0 = (const float*)d_in[3];
    const float* bhh0 = (const float*)d_in[4];
    const float* lw0  = (const float*)d_in[5];
    const float* lb0  = (const float*)d_in[6];
    const float* Wih1 = (const float*)d_in[7];
    const float* Whh1 = (const float*)d_in[8];
    const float* bih1 = (const float*)d_in[9];
    const float* bhh1 = (const float*)d_in[10];
    const float* lw1  = (const float*)d_in[11];
    const float* lb1  = (const float*)d_in[12];

    float* out = (float*)d_out;
    float* seq = out;                                   // (512,256,256)
    float* hs0 = out + (size_t)512 * 256 * 256;
    float* hs1 = hs0 + 256 * 256;
    float* cs0 = hs1 + 256 * 256;
    float* cs1 = cs0 + 256 * 256;

    char* ws = (char*)d_ws;
    unsigned* hG     = (unsigned*)ws;                           // 524288 B
    double*   part   = (double*)  (ws + 524288);                //  65536 B
    float*    skipdu = (float*)   (ws + 524288 + 65536);        //   2048 B
    unsigned* flags  = (unsigned*)(ws + 524288 + 65536 + 2048); //   2048 B

    hipMemsetAsync(flags, 0, 2 * 256 * sizeof(unsigned), stream);

    int one = 1, zero = 0;
    {
        void* args[] = { (void*)&x,   (void*)&Wih0, (void*)&Whh0, (void*)&bih0,
                         (void*)&bhh0,(void*)&lw0,  (void*)&lb0,  (void*)&seq,
                         (void*)&hs0, (void*)&cs0,  (void*)&hG,   (void*)&part,
                         (void*)&skipdu, (void*)&flags, (void*)&one };
        hipLaunchCooperativeKernel(reinterpret_cast<void*>(skiplstm<128>),
                                   dim3(256), dim3(256), args, 0, stream);
    }
    {
        const float* x1 = seq;   // layer-1 input = layer-0 output, in place
        void* args[] = { (void*)&x1,  (void*)&Wih1, (void*)&Whh1, (void*)&bih1,
                         (void*)&bhh1,(void*)&lw1,  (void*)&lb1,  (void*)&seq,
                         (void*)&hs1, (void*)&cs1,  (void*)&hG,   (void*)&part,
                         (void*)&skipdu, (void*)&flags, (void*)&zero };
        hipLaunchCooperativeKernel(reinterpret_cast<void*>(skiplstm<256>),
                                   dim3(256), dim3(256), args, 0, stream);
    }
}

// Round 7
// 3951.358 us; speedup vs baseline: 14.7946x; 1.1316x over previous
//
#include <hip/hip_runtime.h>

#define TSTEPS 512
#define BSZ 256
#define HCH 256

typedef _Float16 f16x8 __attribute__((ext_vector_type(8)));
typedef float    f32x4 __attribute__((ext_vector_type(4)));
typedef unsigned u32x4 __attribute__((ext_vector_type(4)));

__device__ __forceinline__ float sigmoidf_(float v) { return 1.f / (1.f + expf(-v)); }

__device__ __forceinline__ unsigned pack2h(_Float16 a, _Float16 b) {
    union { _Float16 h[2]; unsigned u; } t; t.h[0] = a; t.h[1] = b; return t.u;
}

// agent-scope (L1+L2 bypass) 16-B load, explicitly issued so 16+ can be in
// flight simultaneously (relaxed __hip_atomic_load chains serialize ~500cyc
// each -- the round-6 hidden cost). Consumer must s_waitcnt vmcnt(0) +
// sched_barrier(0) before reading the result (guide rule 18).
__device__ __forceinline__ u32x4 load16_agent(const unsigned* p) {
    u32x4 r;
    asm volatile("global_load_dwordx4 %0, %1, off sc0 sc1" : "=v"(r) : "v"(p));
    return r;
}

// 256 blocks = 16 groups (btile=bid&15) x 16 jtiles; group = 16 batch rows x
// all 256 hc; fence-free flag barrier (round 6, validated). This round:
//  - all LDS operands FRAGMENT-PACKED ([kt][gate][lane] 16-B frags) -> every
//    ds_read_b128 is lane-consecutive, zero bank conflicts.
//  - hG global layout is fragment-ordered; h A-frags are loaded DIRECTLY into
//    registers via asm global_load_dwordx4 sc0 sc1 (pipelined, no LDS hop).
//  - x(t+1) prefetched to registers at step start (drained by arrive's
//    vmcnt(0) => same in-place safety proof), converted to LDS in the overlap
//    window -> nothing heavy sits between cell(t) and the flag post.
template<int IC>
__global__ __launch_bounds__(256, 1)
void skiplstm(const float* __restrict__ x,
              const float* __restrict__ Wih, const float* __restrict__ Whh,
              const float* __restrict__ bih, const float* __restrict__ bhh,
              const float* __restrict__ lw,  const float* __restrict__ lb,
              float* __restrict__ seq_out,
              float* __restrict__ hs_out, float* __restrict__ cs_out,
              unsigned* __restrict__ hG,     // [2][16][2 planes][2048] u32, frag order
              double* __restrict__ part,     // [2][16][16][16]
              float* __restrict__ skipdu,    // [2][256]
              unsigned* __restrict__ flags)  // [2][256]
{
    constexpr bool FIRST = (IC == 128);
    constexpr int K    = IC + HCH;
    constexpr int KT   = K / 32;
    constexpr int KTX  = IC / 32;
    constexpr int KTH  = HCH / 32;        // 8
    constexpr int NWF  = KT * 256;        // W frags per plane
    constexpr int NXF  = KTX * 64;        // x frags per plane
    constexpr int NXFT = NXF / 256 ? NXF / 256 : 1;   // frags/thread (1 or 2)

    __shared__ f16x8 WFh[NWF];            // W hi plane, frag-packed
    __shared__ f16x8 WFl[NWF];            // W lo plane
    __shared__ f16x8 XFh[NXF];            // x hi plane, frag-packed
    __shared__ f16x8 XFl[NXF];
    __shared__ float G[64][17];           // gates [col][row] pad17 (2-way max)
    __shared__ float BV[64];

    const int tid   = threadIdx.x;
    const int bid   = blockIdx.x;
    const int btile = bid & 15;           // group id
    const int jtile = bid >> 4;
    const int lane  = tid & 63;
    const int g     = tid >> 6;           // wave = gate
    const int n16   = lane & 15;
    const int row_c = tid >> 4;           // cell row
    const int q     = tid & 15;           // cell hc-within-jtile
    const int J     = jtile * 16 + q;
    const int brow  = btile * 16 + row_c;
    const int r0    = btile * 16;

    unsigned* gfl    = flags + (FIRST ? 0 : 256) + btile * 16;
    unsigned* myflag = gfl + jtile;

    // ---- one-time: W -> fp16 hi/lo fragment-packed LDS ----
    for (int f = tid; f < NWF; f += 256) {
        const int kt = f >> 8;
        const int rm = f & 255;
        const int gg = rm >> 6;
        const int ln = rm & 63;
        const int grow = gg * HCH + jtile * 16 + (ln & 15);
        const int k0   = kt * 32 + (ln >> 4) * 8;
        const float* src = (k0 < IC) ? (Wih + (size_t)grow * IC + k0)
                                     : (Whh + (size_t)grow * HCH + (k0 - IC));
        const float4 a = *(const float4*)src;
        const float4 b = *(const float4*)(src + 4);
        const float vv[8] = {a.x, a.y, a.z, a.w, b.x, b.y, b.z, b.w};
        f16x8 hv, lv;
        #pragma unroll
        for (int e = 0; e < 8; ++e) {
            const _Float16 hi = (_Float16)vv[e];
            hv[e] = hi; lv[e] = (_Float16)(vv[e] - (float)hi);
        }
        WFh[f] = hv; WFl[f] = lv;
    }
    if (tid < 64) {
        const int grow = (tid >> 4) * HCH + jtile * 16 + (tid & 15);
        BV[tid] = bih[grow] + bhh[grow];
    }
    // ---- zero h(-1) (parity-1 region, idempotent across the group) ----
    {
        unsigned* hz = hG + ((size_t)(16 + btile)) * 2 * 2048;
        for (int i = tid; i < 4096; i += 256)
            __hip_atomic_store(hz + i, 0u, __ATOMIC_RELAXED, __HIP_MEMORY_SCOPE_AGENT);
    }

    const float lwv = lw[J];
    const float lbv = lb[0];
    float h_r = 0.f, c_r = 0.f, u_r = 1.f, du_r;
    int skip_r;
    if (FIRST) { du_r = 0.f; skip_r = 0; }
    else { du_r = skipdu[brow]; skip_r = (skipdu[BSZ + brow] > 0.5f) ? 1 : 0; }

    float4 xr[NXFT][2];                   // x(t+1) register prefetch
    auto xload = [&](int t) {
        #pragma unroll
        for (int s = 0; s < NXFT; ++s) {
            const int f  = tid + s * 256;
            const int kt = f >> 6, ln = f & 63;
            const float* p = x + ((size_t)t * BSZ + r0 + (ln & 15)) * IC
                               + kt * 32 + (ln >> 4) * 8;
            xr[s][0] = *(const float4*)p;
            xr[s][1] = *(const float4*)(p + 4);
        }
    };
    auto xconvert = [&]() {               // regs -> frag-packed LDS (cheap)
        #pragma unroll
        for (int s = 0; s < NXFT; ++s) {
            const int f = tid + s * 256;
            const float vv[8] = {xr[s][0].x, xr[s][0].y, xr[s][0].z, xr[s][0].w,
                                 xr[s][1].x, xr[s][1].y, xr[s][1].z, xr[s][1].w};
            f16x8 hv, lv;
            #pragma unroll
            for (int e = 0; e < 8; ++e) {
                const _Float16 hi = (_Float16)vv[e];
                hv[e] = hi; lv[e] = (_Float16)(vv[e] - (float)hi);
            }
            XFh[f] = hv; XFl[f] = lv;
        }
    };

    auto arrive = [&](unsigned val) {
        asm volatile("s_waitcnt vmcnt(0) lgkmcnt(0)" ::: "memory");
        __syncthreads();
        if (tid == 0)
            __hip_atomic_store(myflag, val, __ATOMIC_RELAXED, __HIP_MEMORY_SCOPE_AGENT);
    };
    auto wait_ = [&](unsigned val) {
        if (tid < 16)
            while (__hip_atomic_load(gfl + tid, __ATOMIC_RELAXED,
                                     __HIP_MEMORY_SCOPE_AGENT) < val)
                __builtin_amdgcn_s_sleep(1);
        __syncthreads();
        asm volatile("" ::: "memory");
    };

    f32x4 accA, accB;
    auto xmfma = [&]() {                  // bias + x-part (h-independent)
        const float bv = BV[g * 16 + n16];
        accA = f32x4{bv, bv, bv, bv};
        accB = f32x4{0.f, 0.f, 0.f, 0.f};
        #pragma unroll
        for (int kt = 0; kt < KTX; ++kt) {
            const f16x8 ah = XFh[kt * 64 + lane];
            const f16x8 al = XFl[kt * 64 + lane];
            const f16x8 bh = WFh[(kt * 4 + g) * 64 + lane];
            const f16x8 bl = WFl[(kt * 4 + g) * 64 + lane];
            accA = __builtin_amdgcn_mfma_f32_16x16x32_f16(ah, bh, accA, 0, 0, 0);
            accB = __builtin_amdgcn_mfma_f32_16x16x32_f16(al, bh, accB, 0, 0, 0);
            accB = __builtin_amdgcn_mfma_f32_16x16x32_f16(ah, bl, accB, 0, 0, 0);
        }
    };

    auto u_advance = [&](double ps) {     // consume part(t-1) -> u/du/skip for t
        double s = ps;
        s += __shfl_xor(s, 1); s += __shfl_xor(s, 2);
        s += __shfl_xor(s, 4); s += __shfl_xor(s, 8);
        const float du_n = sigmoidf_((float)(s + (double)lbv));
        const float bu_p = rintf(u_r);
        float nu, ndu;
        if (skip_r) { nu = fminf(fmaxf(u_r + du_r, 0.f), 1.f) * (1.f - bu_p); ndu = du_r; }
        else        { nu = du_n * bu_p; ndu = du_n; }
        u_r = nu; du_r = ndu;
        skip_r = (nu < 0.5f) ? 1 : 0;     // == (ceil(0.5/nu)-1 > 0)
    };

    // ---- prologue: x(0) -> regs (drained by arrive), convert, x-MFMA ----
    xload(0);
    arrive(1);
    xconvert();
    __syncthreads();
    xmfma();
    wait_(1);

    for (int t = 0; t < TSTEPS; ++t) {
        const int par  = t & 1;
        const int rpar = par ^ 1;

        // ---- issue all long-latency loads up front ----
        u32x4 fh[KTH], fl[KTH];
        double ps = 0.0;
        if (t > 0) {
            const unsigned* b0 = hG + ((size_t)(rpar * 16 + btile)) * 2 * 2048;
            const unsigned* b1 = b0 + 2048;
            #pragma unroll
            for (int ht = 0; ht < KTH; ++ht) {
                fh[ht] = load16_agent(b0 + (ht * 64 + lane) * 4);
                fl[ht] = load16_agent(b1 + (ht * 64 + lane) * 4);
            }
            ps = __hip_atomic_load(part + ((size_t)rpar * 16 + btile) * 256 + tid,
                                   __ATOMIC_RELAXED, __HIP_MEMORY_SCOPE_AGENT);
        } else {
            #pragma unroll
            for (int ht = 0; ht < KTH; ++ht) { fh[ht] = u32x4{0,0,0,0}; fl[ht] = u32x4{0,0,0,0}; }
        }
        if (t + 1 < TSTEPS) xload(t + 1);
        if (t > 0) u_advance(ps);

        // ---- gates h-part MFMAs (A-frags straight from the asm loads) ----
        asm volatile("s_waitcnt vmcnt(0)" ::: "memory");
        __builtin_amdgcn_sched_barrier(0);
        #pragma unroll
        for (int ht = 0; ht < KTH; ++ht) {
            const f16x8 ah = __builtin_bit_cast(f16x8, fh[ht]);
            const f16x8 al = __builtin_bit_cast(f16x8, fl[ht]);
            const f16x8 bh = WFh[((KTX + ht) * 4 + g) * 64 + lane];
            const f16x8 bl = WFl[((KTX + ht) * 4 + g) * 64 + lane];
            accA = __builtin_amdgcn_mfma_f32_16x16x32_f16(ah, bh, accA, 0, 0, 0);
            accB = __builtin_amdgcn_mfma_f32_16x16x32_f16(al, bh, accB, 0, 0, 0);
            accB = __builtin_amdgcn_mfma_f32_16x16x32_f16(ah, bl, accB, 0, 0, 0);
        }
        {
            const f32x4 acc = accA + accB;
            const int c_ = g * 16 + n16, lg4 = (lane >> 4) * 4;
            #pragma unroll
            for (int j = 0; j < 4; ++j) G[c_][lg4 + j] = acc[j];  // C/D: col=lane&15,row=lg*4+j
        }
        __syncthreads();

        // ---- cell ----
        const float bu  = rintf(u_r);       // jnp.round == rint (half-even)
        const float omb = 1.f - bu;
        const float g0 = G[ 0 + q][row_c];
        const float g1 = G[16 + q][row_c];
        const float g2 = G[32 + q][row_c];
        const float g3 = G[48 + q][row_c];
        const float si = sigmoidf_(g0);
        const float sf = sigmoidf_(g1);
        const float tg = tanhf(g2);
        const float so = sigmoidf_(g3);
        const float cc_ = sf * c_r + si * tg;
        const float ch_ = so * tanhf(cc_);
        const float nc_n = cc_ * bu;
        const float nh_n = ch_ * bu;
        const float nh = skip_r ? h_r * omb : nh_n;
        const float nc = skip_r ? c_r * omb : nc_n;
        h_r = nh; c_r = nc;

        // h -> hG (fragment-ordered words; 1 u32/thread via lane pairing)
        const _Float16 hh = (_Float16)nh;
        const _Float16 hl = (_Float16)(nh - (float)hh);
        const unsigned hbits = pack2h(hh, hl);
        const unsigned pbits = (unsigned)__shfl_xor((int)hbits, 1);
        const unsigned word  = (q & 1) ? ((pbits >> 16) | (hbits & 0xffff0000u))
                                       : ((hbits & 0xffffu) | (pbits << 16));
        const int hc0 = J & ~1;
        const int fr  = (hc0 >> 5) * 64 + ((hc0 >> 3) & 3) * 16 + row_c;
        const int dw  = fr * 4 + ((hc0 & 7) >> 1);
        __hip_atomic_store(hG + ((size_t)(par * 16 + btile) * 2 + (q & 1)) * 2048 + dw,
                           word, __ATOMIC_RELAXED, __HIP_MEMORY_SCOPE_AGENT);

        double dd = (double)nc_n * (double)lwv;   // du-dot uses CANDIDATE nc_n
        dd += __shfl_xor(dd, 1); dd += __shfl_xor(dd, 2);
        dd += __shfl_xor(dd, 4); dd += __shfl_xor(dd, 8);
        if (q == 0)
            __hip_atomic_store(part + ((size_t)par * 16 + btile) * 256 + row_c * 16 + jtile,
                               dd, __ATOMIC_RELAXED, __HIP_MEMORY_SCOPE_AGENT);

        arrive((unsigned)(t + 2));

        // ---- overlap window: seq store, x convert, x-part MFMAs ----
        __builtin_nontemporal_store(nh, seq_out + ((size_t)t * BSZ + brow) * HCH + J);
        if (t + 1 < TSTEPS) {
            xconvert();
            __syncthreads();
            xmfma();
        }
        wait_((unsigned)(t + 2));
    }

    // final u/du/skip advance (part(511) flagged by the last barrier)
    {
        const double ps = __hip_atomic_load(
            part + ((size_t)((TSTEPS - 1) & 1) * 16 + btile) * 256 + tid,
            __ATOMIC_RELAXED, __HIP_MEMORY_SCOPE_AGENT);
        u_advance(ps);
    }

    hs_out[(size_t)brow * HCH + J] = h_r;
    cs_out[(size_t)brow * HCH + J] = c_r;
    if (FIRST && jtile == 0 && q == 0) {
        skipdu[brow]       = du_r;
        skipdu[BSZ + brow] = skip_r ? 1.f : 0.f;
    }
}

extern "C" void kernel_launch(void* const* d_in, const int* in_sizes, int n_in,
                              void* d_out, int out_size, void* d_ws, size_t ws_size,
                              hipStream_t stream)
{
    (void)in_sizes; (void)n_in; (void)out_size; (void)ws_size;

    const float* x    = (const float*)d_in[0];
    const float* Wih0 = (const float*)d_in[1];
    const float* Whh0 = (const float*)d_in[2];
    const float* bih0 = (const float*)d_in[3];
    const float* bhh0 = (const float*)d_in[4];
    const float* lw0  = (const float*)d_in[5];
    const float* lb0  = (const float*)d_in[6];
    const float* Wih1 = (const float*)d_in[7];
    const float* Whh1 = (const float*)d_in[8];
    const float* bih1 = (const float*)d_in[9];
    const float* bhh1 = (const float*)d_in[10];
    const float* lw1  = (const float*)d_in[11];
    const float* lb1  = (const float*)d_in[12];

    float* out = (float*)d_out;
    float* seq = out;                                   // (512,256,256)
    float* hs0 = out + (size_t)512 * 256 * 256;
    float* hs1 = hs0 + 256 * 256;
    float* cs0 = hs1 + 256 * 256;
    float* cs1 = cs0 + 256 * 256;

    char* ws = (char*)d_ws;
    unsigned* hG     = (unsigned*)ws;                           // 524288 B
    double*   part   = (double*)  (ws + 524288);                //  65536 B
    float*    skipdu = (float*)   (ws + 524288 + 65536);        //   2048 B
    unsigned* flags  = (unsigned*)(ws + 524288 + 65536 + 2048); //   2048 B

    hipMemsetAsync(flags, 0, 2 * 256 * sizeof(unsigned), stream);

    {
        void* args[] = { (void*)&x,   (void*)&Wih0, (void*)&Whh0, (void*)&bih0,
                         (void*)&bhh0,(void*)&lw0,  (void*)&lb0,  (void*)&seq,
                         (void*)&hs0, (void*)&cs0,  (void*)&hG,   (void*)&part,
                         (void*)&skipdu, (void*)&flags };
        hipLaunchCooperativeKernel(reinterpret_cast<void*>(skiplstm<128>),
                                   dim3(256), dim3(256), args, 0, stream);
    }
    {
        const float* x1 = seq;   // layer-1 input = layer-0 output, in place
        void* args[] = { (void*)&x1,  (void*)&Wih1, (void*)&Whh1, (void*)&bih1,
                         (void*)&bhh1,(void*)&lw1,  (void*)&lb1,  (void*)&seq,
                         (void*)&hs1, (void*)&cs1,  (void*)&hG,   (void*)&part,
                         (void*)&skipdu, (void*)&flags };
        hipLaunchCooperativeKernel(reinterpret_cast<void*>(skiplstm<256>),
                                   dim3(256), dim3(256), args, 0, stream);
    }
}